// Round 4
// baseline (512458.008 us; speedup 1.0000x reference)
//
#include <hip/hip_runtime.h>

#define NTHR 512
#define NBLK 256

// problem dims
#define B_    256
#define TE_   300
#define T_    600
#define NIN_  128
#define H_    512
#define EMB_  32
#define OUT_HE_OFS 768000ull   // 256*600*5

// ---- workspace layout (float offsets) ----
constexpr size_t OF_BAR  = 0;          // 1024
constexpr size_t OF_XEMB = 1024;       // 256*32
constexpr size_t OF_HA   = 9216;       // 2 * 256*512
constexpr size_t OF_HB   = 271360;     // 2 * 256*512
constexpr size_t OF_PV   = 533504;     // 256*8
constexpr size_t OF_S1   = 535552;     // 256*128
constexpr size_t OF_S2   = 568320;     // 256*128
constexpr size_t OF_BC   = 601088;     // 4 phases * 512 * 4 combined biases
constexpr size_t OF_E0I  = 609280;     // 32*40*48*4
constexpr size_t OF_E0H  = 855040;     // 32*128*48*4
constexpr size_t OF_E1I  = 1641472;
constexpr size_t OF_E1H  = 2427904;
constexpr size_t OF_D0I  = 3214336;    // 32*34*48*4 (K=133 zero-padded to 136)
constexpr size_t OF_D0H  = 3423232;
constexpr size_t OF_D1I  = 4209664;
constexpr size_t OF_D1H  = 4996096;
constexpr size_t OF_FH   = 5782528;    // 32*128*8*4
constexpr size_t WS_END  = 5913600;    // ~23.7 MB

// ---------------- init ----------------
__global__ void k_init(float* __restrict__ ws, const float* __restrict__ pv_init,
                       const int* __restrict__ scen, const float* __restrict__ emb,
                       const float* ebi0, const float* ebh0, const float* ebi1, const float* ebh1,
                       const float* dbi0, const float* dbh0, const float* dbi1, const float* dbh1) {
  const size_t N0 = 1024, N1 = N0 + 8192, N2 = N1 + 2048, N3 = N2 + 8192,
               N4 = N3 + 131072, N5 = N4 + 131072;
  size_t stride = (size_t)gridDim.x * blockDim.x;
  for (size_t x = (size_t)blockIdx.x * blockDim.x + threadIdx.x; x < N5; x += stride) {
    if (x < N0) {
      ((unsigned*)ws)[x] = 0u;
    } else if (x < N1) {
      size_t r = x - N0; int b = (int)(r >> 5), e = (int)(r & 31);
      ws[OF_XEMB + r] = emb[scen[b] * EMB_ + e];
    } else if (x < N2) {
      size_t r = x - N1; int b = (int)(r >> 3), p = (int)(r & 7);
      ws[OF_PV + r] = (p < 5) ? pv_init[b * 5 + p] : 0.f;
    } else if (x < N3) {
      size_t r = x - N2; int q = (int)(r & 3), hid = (int)((r >> 2) & 511), ph = (int)(r >> 11);
      const float* bi = (ph == 0) ? ebi0 : (ph == 1) ? ebi1 : (ph == 2) ? dbi0 : dbi1;
      const float* bh = (ph == 0) ? ebh0 : (ph == 1) ? ebh1 : (ph == 2) ? dbh0 : dbh1;
      float v;
      if (q == 0) v = bi[hid] + bh[hid];
      else if (q == 1) v = bi[512 + hid] + bh[512 + hid];
      else if (q == 2) v = bi[1024 + hid];
      else v = bh[1024 + hid];
      ws[OF_BC + r] = v;
    } else if (x < N4) {
      ws[OF_HA + 131072 + (x - N3)] = 0.f;   // hA slot 1 = 0 (encoder h0)
    } else {
      ws[OF_HB + 131072 + (x - N4)] = 0.f;   // hB slot 1 = 0
    }
  }
}

// weight rearrange: dst f4[g][kq][48]; col c' = cg*6 + gate*2 + h2 -> src col gate*512+g*16+cg*2+h2
__global__ void k_rearr(float4* __restrict__ dst, const float* __restrict__ src, int Kreal, int KQ) {
  int n = 32 * KQ * 48;
  for (int idx = blockIdx.x * blockDim.x + threadIdx.x; idx < n; idx += gridDim.x * blockDim.x) {
    int g = idx / (KQ * 48), r = idx % (KQ * 48), kq = r / 48, c = r % 48;
    int cg = c / 6, ci = c % 6, gate = ci >> 1, h2 = ci & 1;
    size_t col = (size_t)(gate * 512 + g * 16 + cg * 2 + h2);
    int k = kq * 4;
    float4 v;
    v.x = (k + 0 < Kreal) ? src[col * Kreal + k + 0] : 0.f;
    v.y = (k + 1 < Kreal) ? src[col * Kreal + k + 1] : 0.f;
    v.z = (k + 2 < Kreal) ? src[col * Kreal + k + 2] : 0.f;
    v.w = (k + 3 < Kreal) ? src[col * Kreal + k + 3] : 0.f;
    dst[idx] = v;
  }
}

// fc1/he1: dst f4[g][kq(128)][8]; c<4: fc1 row g*4+c, else he1 row g*4+c-4
__global__ void k_rearr_fh(float4* __restrict__ dst, const float* __restrict__ fc1,
                           const float* __restrict__ he1) {
  int n = 32 * 128 * 8;
  for (int idx = blockIdx.x * blockDim.x + threadIdx.x; idx < n; idx += gridDim.x * blockDim.x) {
    int g = idx / (128 * 8), r = idx % (128 * 8), kq = r / 8, c = r % 8;
    const float* s = (c < 4) ? fc1 : he1;
    size_t row = (size_t)(g * 4 + (c & 3));
    int k = kq * 4;
    float4 v = { s[row * 512 + k], s[row * 512 + k + 1], s[row * 512 + k + 2], s[row * 512 + k + 3] };
    dst[idx] = v;
  }
}

// ---------------- device helpers ----------------
__device__ __forceinline__ float sigm(float x) { return 1.f / (1.f + __expf(-x)); }
__device__ __forceinline__ float tanhx(float x) { float e = __expf(2.f * x); return 1.f - 2.f / (e + 1.f); }
__device__ __forceinline__ float f4c(const float4& v, int k) {
  switch (k) { case 0: return v.x; case 1: return v.y; case 2: return v.z; default: return v.w; }
}

// two-level sense-reversing grid barrier
__device__ __forceinline__ void bar_sync(unsigned* bar, int wg) {
  __syncthreads();
  if (threadIdx.x == 0) {
    unsigned gen = __hip_atomic_load(&bar[520], __ATOMIC_RELAXED, __HIP_MEMORY_SCOPE_AGENT);
    unsigned n = __hip_atomic_fetch_add(&bar[(wg >> 4) << 5], 1u, __ATOMIC_ACQ_REL, __HIP_MEMORY_SCOPE_AGENT);
    if (n == 15u) {
      unsigned r = __hip_atomic_fetch_add(&bar[512], 1u, __ATOMIC_ACQ_REL, __HIP_MEMORY_SCOPE_AGENT);
      if (r == 15u) {
        __hip_atomic_store(&bar[512], 0u, __ATOMIC_RELAXED, __HIP_MEMORY_SCOPE_AGENT);
#pragma unroll
        for (int i = 0; i < 16; ++i)
          __hip_atomic_store(&bar[i << 5], 0u, __ATOMIC_RELAXED, __HIP_MEMORY_SCOPE_AGENT);
        __hip_atomic_store(&bar[520], gen + 1u, __ATOMIC_RELEASE, __HIP_MEMORY_SCOPE_AGENT);
      }
    }
    while (__hip_atomic_load(&bar[520], __ATOMIC_ACQUIRE, __HIP_MEMORY_SCOPE_AGENT) == gen)
      __builtin_amdgcn_s_sleep(1);
  }
  __syncthreads();
}

// ============ GRU phase: M=32 rows x N=48 gate-cols, register-tiled ============
// thread: pos=tid&31 (bq=pos>>3: 8 rows; cg=pos&7: 6 cols), ks=tid>>5: k-slice (4 consecutive k per 64-tile)
// KIND 0: enc L0 (x_cv tiles 0-1, xemb tile 2[32k]); 1: plain [256][512] input; 2: dec L0 (x_tgt 0-1, s_pv tile 2[8k])
template <int KIND>
__device__ void gru2(const float* __restrict__ actA, const float* __restrict__ actB, int t,
                     const float4* __restrict__ wi4, const int KQi, const float4* __restrict__ wh4,
                     const float* __restrict__ hprev, float* __restrict__ hout,
                     const float* __restrict__ bcp, int b0, int g,
                     float4* __restrict__ s_w4, float* __restrict__ sh,
                     const float* __restrict__ s_pvl) {
  constexpr int NTI = (KIND == 1) ? 8 : 3;
  constexpr int NT = NTI + 8;
  const int tid = threadIdx.x;
  const int pos = tid & 31, ks = tid >> 5;
  const int bq = pos >> 3, cg = pos & 7;
  const int r0 = b0 + bq * 8;
  const int kin = ks * 4;
  const int t512 = tid + 512;
  const int st0 = (tid / 48) * 49 + (tid % 48);
  const int st1 = (t512 / 48) * 49 + (t512 % 48);
  const int wrb = ks * 49 + cg * 6;

  float acc[8][6], accH[8][2];
#pragma unroll
  for (int j = 0; j < 8; ++j) {
    accH[j][0] = 0.f; accH[j][1] = 0.f;
#pragma unroll
    for (int i = 0; i < 6; ++i) acc[j][i] = 0.f;
  }

  float4 Ac[8], An[8], wsA0, wsA1, wsB0, wsB1;
  int n4c = 0, n4n = 0;
  bool actc = false, actn = false;

  auto prefW = [&](int ktn, float4& w0, float4& w1, int& n4) {
    const float4* base;
    if (ktn < NTI) {
      int kq0 = ktn * 16;
      int kqn = (KQi - kq0 < 16) ? (KQi - kq0) : 16;
      n4 = kqn * 48;
      base = wi4 + ((size_t)g * KQi + kq0) * 48;
    } else {
      n4 = 768;
      base = wh4 + ((size_t)g * 128 + (ktn - NTI) * 16) * 48;
    }
    if (tid < n4) w0 = base[tid];
    if (t512 < n4) w1 = base[t512];
  };
  auto prefA = [&](int ktn, float4* A) -> bool {
    if (ktn >= NTI) {
      const float* b = hprev + (ktn - NTI) * 64 + kin;
#pragma unroll
      for (int j = 0; j < 8; ++j) A[j] = *(const float4*)(b + (size_t)(r0 + j) * H_);
      return true;
    }
    if (KIND == 1) {
      const float* b = actA + ktn * 64 + kin;
#pragma unroll
      for (int j = 0; j < 8; ++j) A[j] = *(const float4*)(b + (size_t)(r0 + j) * H_);
      return true;
    }
    if (KIND == 0) {
      if (ktn < 2) {
        const float* b = actA + (size_t)t * NIN_ + ktn * 64 + kin;
#pragma unroll
        for (int j = 0; j < 8; ++j) A[j] = *(const float4*)(b + (size_t)(r0 + j) * (TE_ * NIN_));
        return true;
      }
      if (ks < 8) {
        const float* b = actB + kin;
#pragma unroll
        for (int j = 0; j < 8; ++j) A[j] = *(const float4*)(b + (size_t)(r0 + j) * EMB_);
        return true;
      }
      return false;
    }
    // KIND 2
    if (ktn < 2) {
      const float* b = actA + (size_t)t * NIN_ + ktn * 64 + kin;
#pragma unroll
      for (int j = 0; j < 8; ++j) A[j] = *(const float4*)(b + (size_t)(r0 + j) * (T_ * NIN_));
      return true;
    }
    if (ks < 2) {
      int rl = bq * 8;
#pragma unroll
      for (int j = 0; j < 8; ++j) A[j] = *(const float4*)(s_pvl + (rl + j) * 8 + kin);
      return true;
    }
    return false;
  };

  actc = prefA(0, Ac);
  prefW(0, wsA0, wsA1, n4c);

#pragma unroll
  for (int kt = 0; kt < NT; ++kt) {
    __syncthreads();   // previous tile's compute done reading LDS
    if (tid < n4c) s_w4[st0] = wsA0;
    if (t512 < n4c) s_w4[st1] = wsA1;
    __syncthreads();
    if (kt + 1 < NT) { prefW(kt + 1, wsB0, wsB1, n4n); actn = prefA(kt + 1, An); }
    if (actc) {
      float4 Wr[6];
#pragma unroll
      for (int i = 0; i < 6; ++i) Wr[i] = s_w4[wrb + i];
      const bool hidp = (kt >= NTI);
#pragma unroll
      for (int kk = 0; kk < 4; ++kk) {
#pragma unroll
        for (int j = 0; j < 8; ++j) {
          float a = f4c(Ac[j], kk);
          acc[j][0] = fmaf(a, f4c(Wr[0], kk), acc[j][0]);
          acc[j][1] = fmaf(a, f4c(Wr[1], kk), acc[j][1]);
          acc[j][2] = fmaf(a, f4c(Wr[2], kk), acc[j][2]);
          acc[j][3] = fmaf(a, f4c(Wr[3], kk), acc[j][3]);
          if (hidp) {
            accH[j][0] = fmaf(a, f4c(Wr[4], kk), accH[j][0]);
            accH[j][1] = fmaf(a, f4c(Wr[5], kk), accH[j][1]);
          } else {
            acc[j][4] = fmaf(a, f4c(Wr[4], kk), acc[j][4]);
            acc[j][5] = fmaf(a, f4c(Wr[5], kk), acc[j][5]);
          }
        }
      }
    }
    if (kt + 1 < NT) {
#pragma unroll
      for (int j = 0; j < 8; ++j) Ac[j] = An[j];
      wsA0 = wsB0; wsA1 = wsB1; n4c = n4n; actc = actn;
    }
  }

  // ---- k-split reduction, NO ATOMICS ----
  // wave w holds k-slices {2w, 2w+1}; pair-sum across halves via shfl_xor(32),
  // then 8 wave-planes fold to 4 LDS planes (waves 0-3 store, waves 4-7 RMW).
  const int wv = tid >> 6;
  const int half = (tid >> 5) & 1;
#pragma unroll
  for (int j = 0; j < 8; ++j) {
#pragma unroll
    for (int i = 0; i < 6; ++i) acc[j][i] += __shfl_xor(acc[j][i], 32);
    accH[j][0] += __shfl_xor(accH[j][0], 32);
    accH[j][1] += __shfl_xor(accH[j][1], 32);
  }
  if (wv < 4) {
    float* pb = sh + wv * 2080;
#pragma unroll
    for (int jj = 0; jj < 4; ++jj) {
      const int j = (half << 2) + jj;
      float* bp = pb + (bq * 8 + j) * 65 + cg;
      bp[0]  = acc[j][0]; bp[8]  = acc[j][1]; bp[16] = acc[j][2]; bp[24] = acc[j][3];
      bp[32] = acc[j][4]; bp[40] = acc[j][5]; bp[48] = accH[j][0]; bp[56] = accH[j][1];
    }
  }
  __syncthreads();
  if (wv >= 4) {
    float* pb = sh + (wv - 4) * 2080;
#pragma unroll
    for (int jj = 0; jj < 4; ++jj) {
      const int j = (half << 2) + jj;
      float* bp = pb + (bq * 8 + j) * 65 + cg;
      bp[0]  += acc[j][0]; bp[8]  += acc[j][1]; bp[16] += acc[j][2]; bp[24] += acc[j][3];
      bp[32] += acc[j][4]; bp[40] += acc[j][5]; bp[48] += accH[j][0]; bp[56] += accH[j][1];
    }
  }
  __syncthreads();

  // epilogue: r = tid>>4 (0..31), hc = tid&15
  {
    const int r = tid >> 4, hc = tid & 15;
    const int cgE = hc >> 1, h2 = hc & 1;
    const float* s0 = sh + r * 65 + cgE + (h2 << 3);
    float R = 0.f, Z = 0.f, NI = 0.f, NH = 0.f;
#pragma unroll
    for (int w = 0; w < 4; ++w) {
      const float* q = s0 + w * 2080;
      R += q[0]; Z += q[16]; NI += q[32]; NH += q[48];
    }
    const int hid = g * 16 + hc;
    float4 bc = *(const float4*)(bcp + hid * 4);
    float rr = sigm(R + bc.x);
    float zz = sigm(Z + bc.y);
    float nn = tanhx(NI + bc.z + rr * (NH + bc.w));
    float hp = hprev[(size_t)(b0 + r) * H_ + hid];
    hout[(size_t)(b0 + r) * H_ + hid] = (1.f - zz) * nn + zz * hp;
  }
  __syncthreads();
}

// ============ H1 phase: s1/s2 = relu(d2 @ [fc1;he1]^T + b), M=32 x N=8 ============
__device__ void h1_tile(const float* __restrict__ d2, const float4* __restrict__ wfh4,
                        const float* __restrict__ fc1_b, const float* __restrict__ he1_b,
                        float* __restrict__ s1g, float* __restrict__ s2g,
                        int b0, int g, float4* __restrict__ s_w4, float* __restrict__ sh) {
  const int tid = threadIdx.x;
  const int pos = tid & 31, ks = tid >> 5;
  const int bq = pos >> 3, cg = pos & 7;
  const int r0 = b0 + bq * 8, kin = ks * 4;
  const int st0 = (tid < 128) ? (tid / 8) * 9 + (tid % 8) : 0;
  float acc[8];
#pragma unroll
  for (int j = 0; j < 8; ++j) acc[j] = 0.f;
  float4 Ac[8], An[8], wsA = {0,0,0,0}, wsB = {0,0,0,0};
  auto pw = [&](int ktn, float4& w) { if (tid < 128) w = wfh4[((size_t)g * 128 + ktn * 16) * 8 + tid]; };
  auto pa = [&](int ktn, float4* A) {
    const float* b = d2 + ktn * 64 + kin;
#pragma unroll
    for (int j = 0; j < 8; ++j) A[j] = *(const float4*)(b + (size_t)(r0 + j) * H_);
  };
  pa(0, Ac); pw(0, wsA);
#pragma unroll
  for (int kt = 0; kt < 8; ++kt) {
    __syncthreads();
    if (tid < 128) s_w4[st0] = wsA;
    __syncthreads();
    if (kt + 1 < 8) { pw(kt + 1, wsB); pa(kt + 1, An); }
    float4 Wr = s_w4[ks * 9 + cg];
#pragma unroll
    for (int kk = 0; kk < 4; ++kk)
#pragma unroll
      for (int j = 0; j < 8; ++j)
        acc[j] = fmaf(f4c(Ac[j], kk), f4c(Wr, kk), acc[j]);
    if (kt + 1 < 8) {
#pragma unroll
      for (int j = 0; j < 8; ++j) Ac[j] = An[j];
      wsA = wsB;
    }
  }
  // reduction, NO ATOMICS: shfl pair-sum + 4 planes [4][32][9]
  const int wv = tid >> 6, half = (tid >> 5) & 1;
#pragma unroll
  for (int j = 0; j < 8; ++j) acc[j] += __shfl_xor(acc[j], 32);
  if (wv < 4) {
#pragma unroll
    for (int jj = 0; jj < 4; ++jj) {
      const int j = (half << 2) + jj;
      sh[wv * 288 + (bq * 8 + j) * 9 + cg] = acc[j];
    }
  }
  __syncthreads();
  if (wv >= 4) {
#pragma unroll
    for (int jj = 0; jj < 4; ++jj) {
      const int j = (half << 2) + jj;
      sh[(wv - 4) * 288 + (bq * 8 + j) * 9 + cg] += acc[j];
    }
  }
  __syncthreads();
  if (tid < 256) {
    int r = tid >> 3, c = tid & 7;
    float v = sh[r * 9 + c] + sh[288 + r * 9 + c] + sh[576 + r * 9 + c] + sh[864 + r * 9 + c];
    if (c < 4) s1g[(size_t)(b0 + r) * 128 + g * 4 + c] = fmaxf(v + fc1_b[g * 4 + c], 0.f);
    else       s2g[(size_t)(b0 + r) * 128 + g * 4 + (c - 4)] = fmaxf(v + he1_b[g * 4 + c - 4], 0.f);
  }
  __syncthreads();
}

// ---------------- persistent kernel ----------------
__global__ __launch_bounds__(NTHR, 2) void k_main(
    float* __restrict__ ws, const float* __restrict__ x_cv, const float* __restrict__ x_tgt,
    const float* __restrict__ fc1_b, const float* __restrict__ fc2_W, const float* __restrict__ fc2_b,
    const float* __restrict__ he1_b, const float* __restrict__ he2_W, const float* __restrict__ he2_b,
    float* __restrict__ out) {
  __shared__ __align__(16) float4 s_w4[784];
  __shared__ __align__(16) float sh[8320];   // 4 planes x 32 x 65
  __shared__ __align__(16) float s_pv[256];
  __shared__ __align__(16) float s_hd[512];

  const int tid = threadIdx.x;
  const int wg = blockIdx.x;
  const int ji = wg & 31;   // hidden group: WGs sharing ji are congruent mod 8 -> same XCD
  const int bi = wg >> 5;   // batch group
  const int b0 = bi << 5;

  unsigned* bar = (unsigned*)ws;
  const float* xemb = ws + OF_XEMB;
  float* hA[2] = {ws + OF_HA, ws + OF_HA + 131072};
  float* hB[2] = {ws + OF_HB, ws + OF_HB + 131072};
  const float* pvst = ws + OF_PV;
  float* s1g = ws + OF_S1;
  float* s2g = ws + OF_S2;
  const float* bc = ws + OF_BC;
  const float4* wE0I = (const float4*)(ws + OF_E0I); const float4* wE0H = (const float4*)(ws + OF_E0H);
  const float4* wE1I = (const float4*)(ws + OF_E1I); const float4* wE1H = (const float4*)(ws + OF_E1H);
  const float4* wD0I = (const float4*)(ws + OF_D0I); const float4* wD0H = (const float4*)(ws + OF_D0H);
  const float4* wD1I = (const float4*)(ws + OF_D1I); const float4* wD1H = (const float4*)(ws + OF_D1H);
  const float4* wFH  = (const float4*)(ws + OF_FH);

  // ======== encoder (L0 + L1 pipelined, L1 lags one step) ========
  for (int s = 0; s <= TE_; ++s) {
    if (s < TE_)
      gru2<0>(x_cv, xemb, s, wE0I, 40, wE0H, hA[(s + 1) & 1], hA[s & 1],
              bc + 0 * 2048, b0, ji, s_w4, sh, nullptr);
    if (s >= 1)
      gru2<1>(hA[(s + 1) & 1], nullptr, 0, wE1I, 128, wE1H, hB[s & 1], hB[(s + 1) & 1],
              bc + 1 * 2048, b0, ji, s_w4, sh, nullptr);
    bar_sync(bar, wg);
  }

  // ======== decoder ========
  for (int t = 0; t <= T_; ++t) {
    if (t == 0) {
      if (tid < 256) s_pv[tid] = pvst[(b0 << 3) + tid];
      __syncthreads();
    } else {
      {  // pv = s1 @ fc2^T + b (redundant per WG for feedback); k-split 2
        const int rr = tid & 31, p = (tid >> 5) & 7, k2 = tid >> 8;
        if (p < 5) {
          float a = 0.f;
          const float4* s4 = (const float4*)(s1g + (size_t)(b0 + rr) * 128) + k2 * 16;
          const float4* w4 = (const float4*)(fc2_W + (size_t)p * 128) + k2 * 16;
#pragma unroll
          for (int q = 0; q < 16; ++q) {
            float4 av = s4[q], wv = w4[q];
            a = fmaf(av.x, wv.x, a); a = fmaf(av.y, wv.y, a);
            a = fmaf(av.z, wv.z, a); a = fmaf(av.w, wv.w, a);
          }
          s_hd[rr * 16 + p * 2 + k2] = a;
        }
      }
      __syncthreads();
      if (tid < 256) {
        int rr = tid & 31, p = tid >> 3 & 7;
        rr = tid >> 3; p = tid & 7;
        s_pv[rr * 8 + p] = (p < 5) ? (s_hd[rr * 16 + p * 2] + s_hd[rr * 16 + p * 2 + 1] + fc2_b[p]) : 0.f;
      }
      __syncthreads();
      if (ji == 1 && tid < 160) {
        int rr = tid & 31, p = tid >> 5;
        out[((size_t)(b0 + rr) * T_ + (t - 1)) * 5 + p] = s_pv[rr * 8 + p];
      }
      if (ji == 0) {
        int rr = tid & 31, e = tid >> 5;
        float a = he2_b[e];
        const float4* s4 = (const float4*)(s2g + (size_t)(b0 + rr) * 128);
        const float4* w4 = (const float4*)(he2_W + (size_t)e * 128);
#pragma unroll
        for (int q = 0; q < 32; ++q) {
          float4 av = s4[q], wv = w4[q];
          a = fmaf(av.x, wv.x, a); a = fmaf(av.y, wv.y, a);
          a = fmaf(av.z, wv.z, a); a = fmaf(av.w, wv.w, a);
        }
        out[OUT_HE_OFS + ((size_t)(b0 + rr) * T_ + (t - 1)) * 16 + e] = a;
      }
    }

    if (t < T_) {
      gru2<2>(x_tgt, nullptr, t, wD0I, 34, wD0H, hA[(t + 1) & 1], hA[t & 1],
              bc + 2 * 2048, b0, ji, s_w4, sh, s_pv);
      bar_sync(bar, wg);
      gru2<1>(hA[t & 1], nullptr, 0, wD1I, 128, wD1H, hB[(t + 1) & 1], hB[t & 1],
              bc + 3 * 2048, b0, ji, s_w4, sh, nullptr);
      bar_sync(bar, wg);
      h1_tile(hB[t & 1], wFH, fc1_b, he1_b, s1g, s2g, b0, ji, s_w4, sh);
      bar_sync(bar, wg);
    }
  }
}

// ---------------- host ----------------
extern "C" void kernel_launch(void* const* d_in, const int* in_sizes, int n_in,
                              void* d_out, int out_size, void* d_ws, size_t ws_size,
                              hipStream_t stream) {
  float* ws = (float*)d_ws;
  const float* x_cv   = (const float*)d_in[0];
  const float* x_tgt  = (const float*)d_in[1];
  const float* pv_init= (const float*)d_in[2];
  const int*   scen   = (const int*)d_in[3];
  const float* emb    = (const float*)d_in[4];
  const float* eWih0  = (const float*)d_in[5];
  const float* eWhh0  = (const float*)d_in[6];
  const float* ebi0   = (const float*)d_in[7];
  const float* ebh0   = (const float*)d_in[8];
  const float* eWih1  = (const float*)d_in[9];
  const float* eWhh1  = (const float*)d_in[10];
  const float* ebi1   = (const float*)d_in[11];
  const float* ebh1   = (const float*)d_in[12];
  const float* dWih0  = (const float*)d_in[13];
  const float* dWhh0  = (const float*)d_in[14];
  const float* dbi0   = (const float*)d_in[15];
  const float* dbh0   = (const float*)d_in[16];
  const float* dWih1  = (const float*)d_in[17];
  const float* dWhh1  = (const float*)d_in[18];
  const float* dbi1   = (const float*)d_in[19];
  const float* dbh1   = (const float*)d_in[20];
  const float* fc1W   = (const float*)d_in[21];
  const float* fc1b   = (const float*)d_in[22];
  const float* fc2W   = (const float*)d_in[23];
  const float* fc2b   = (const float*)d_in[24];
  const float* he1W   = (const float*)d_in[25];
  const float* he1b   = (const float*)d_in[26];
  const float* he2W   = (const float*)d_in[27];
  const float* he2b   = (const float*)d_in[28];

  hipLaunchKernelGGL(k_init, dim3(512), dim3(256), 0, stream, ws, pv_init, scen, emb,
                     ebi0, ebh0, ebi1, ebh1, dbi0, dbh0, dbi1, dbh1);
  hipLaunchKernelGGL(k_rearr, dim3(512), dim3(256), 0, stream, (float4*)(ws + OF_E0I), eWih0, 160, 40);
  hipLaunchKernelGGL(k_rearr, dim3(512), dim3(256), 0, stream, (float4*)(ws + OF_E0H), eWhh0, 512, 128);
  hipLaunchKernelGGL(k_rearr, dim3(512), dim3(256), 0, stream, (float4*)(ws + OF_E1I), eWih1, 512, 128);
  hipLaunchKernelGGL(k_rearr, dim3(512), dim3(256), 0, stream, (float4*)(ws + OF_E1H), eWhh1, 512, 128);
  hipLaunchKernelGGL(k_rearr, dim3(512), dim3(256), 0, stream, (float4*)(ws + OF_D0I), dWih0, 133, 34);
  hipLaunchKernelGGL(k_rearr, dim3(512), dim3(256), 0, stream, (float4*)(ws + OF_D0H), dWhh0, 512, 128);
  hipLaunchKernelGGL(k_rearr, dim3(512), dim3(256), 0, stream, (float4*)(ws + OF_D1I), dWih1, 512, 128);
  hipLaunchKernelGGL(k_rearr, dim3(512), dim3(256), 0, stream, (float4*)(ws + OF_D1H), dWhh1, 512, 128);
  hipLaunchKernelGGL(k_rearr_fh, dim3(256), dim3(256), 0, stream, (float4*)(ws + OF_FH), fc1W, he1W);

  hipLaunchKernelGGL(k_main, dim3(NBLK), dim3(NTHR), 0, stream,
                     ws, x_cv, x_tgt, fc1b, fc2W, fc2b, he1b, he2W, he2b, (float*)d_out);
}